// Round 10
// baseline (178.327 us; speedup 1.0000x reference)
//
#include <hip/hip_runtime.h>

// Problem constants (fixed by setup_inputs) — float inputs are FP32.
#define NB 8
#define NN 4096
#define DEG 16
#define UN 128
#define NE (NN*DEG)
#define SC 1.2304489f   // fp32(log(17)/log(10))

typedef unsigned short u16;
typedef __attribute__((ext_vector_type(8))) short short8;  // 8 bf16 = 4 VGPRs
typedef __attribute__((ext_vector_type(4))) float f32x4;

__device__ __forceinline__ float b2f(u16 v) { return __uint_as_float(((unsigned)v) << 16); }
// round-to-nearest-even fp32 -> bf16
__device__ __forceinline__ u16 f2b(float f) {
    unsigned u = __float_as_uint(f);
    unsigned r = ((u >> 16) & 1u) + 0x7FFFu;
    return (u16)((u + r) >> 16);
}

// ---------------------------------------------------------------------------
// Prep: (a) fold W -> transposed bf16 B-mats + BN consts (blocks 0..383),
//       (b) convert x fp32 -> bf16 (blocks 384..2431), (c) zero counters.
//   AsumT[d][u][j] = ((W0+s(W1+W2))/16 + W6+s(W7+W8))^T, AmaxT = (W3+s(W4+W5))^T
//   k = gamma*rsqrt(var+eps), c = beta - mean*k
// grid 2432, block 256.
// ---------------------------------------------------------------------------
__global__ void pna10_prep(const float* W, const float* bias, const float* gamma,
                           const float* beta, const float* mmean, const float* mvar,
                           const float* xattr,
                           u16* AsumT, u16* AmaxT, float* biasf, float* kv, float* cv,
                           u16* bufX, int* counters) {
    const int bid = blockIdx.x;
    const int t = threadIdx.x;  // 256
    if (bid == 0 && t < 16) counters[t] = 0;
    if (bid < 384) {
        if (t < 128) {
            const int d = bid >> 7;        // 0..2
            const int j = bid & 127;
            const int u = t;
            const float* Wd = W + (size_t)d * 9 * UN * UN;
            float w[9];
#pragma unroll
            for (int r = 0; r < 9; r++) w[r] = Wd[(size_t)(r * UN + j) * UN + u];
            float asum = (w[0] + SC * (w[1] + w[2])) * 0.0625f + w[6] + SC * (w[7] + w[8]);
            float amax = w[3] + SC * (w[4] + w[5]);
            AsumT[((size_t)d * UN + u) * UN + j] = f2b(asum);
            AmaxT[((size_t)d * UN + u) * UN + j] = f2b(amax);
            if (j == 0) {
                float k = gamma[d * UN + u] * rsqrtf(mvar[d * UN + u] + 1e-3f);
                kv[d * UN + u] = k;
                cv[d * UN + u] = beta[d * UN + u] - mmean[d * UN + u] * k;
                biasf[d * UN + u] = bias[d * UN + u];
            }
        }
        return;
    }
    // x conversion: 2048 blocks x 256 thr x 8 elems = 4,194,304 = 8*4096*128
    const size_t base = (size_t)(bid - 384) * 2048 + (size_t)t * 8;
    float4 x0 = *(const float4*)(xattr + base);
    float4 x1 = *(const float4*)(xattr + base + 4);
    u16 o[8] = { f2b(x0.x), f2b(x0.y), f2b(x0.z), f2b(x0.w),
                 f2b(x1.x), f2b(x1.y), f2b(x1.z), f2b(x1.w) };
    *(uint4*)(bufX + base) = *(const uint4*)o;
}

// ---------------------------------------------------------------------------
// PNA layer, MFMA path. grid 512 (b = bid&7 XCD-pin, 64-node tile), block 512.
// MODE 1: bf16 x in -> bf16 x out.
// MODE 2: bf16 x in -> fused per-tile node-sum (partial); the last finishing
//         block of each batch (device-scope counter) runs the readout MLP.
// Phase 1: gather-aggregate -> s_sum/s_max bf16 in LDS [64][136].
// Phase 2: 8 waves: wave w -> m-rows (w&3)*16..+15, nt-half (w>>2)*4..+3;
//          C = s_sum@Asum + s_max@Amax via mfma_f32_16x16x32_bf16 (K=128 each).
// ---------------------------------------------------------------------------
template <int MODE>
__global__ void pna10_layer(const u16* __restrict__ xin, const int* __restrict__ eidx,
                            const u16* __restrict__ AsumT, const u16* __restrict__ AmaxT,
                            const float* __restrict__ biasf, const float* __restrict__ kv,
                            const float* __restrict__ cv,
                            u16* __restrict__ xout, float* __restrict__ partial,
                            int* __restrict__ counters,
                            const float* __restrict__ Wp1, const float* __restrict__ bp1,
                            const float* __restrict__ Wp2, const float* __restrict__ bp2,
                            float* __restrict__ out, int d) {
    const int bid = blockIdx.x;
    const int b = bid & 7;               // batch -> XCD pin
    const int tile = bid >> 3;           // 0..63
    const int node0 = tile * 64;
    const int t = threadIdx.x;           // 512

    __shared__ u16 sS[64][136];          // s_sum bf16 (row stride 272 B)
    __shared__ u16 sM[64][136];          // s_max bf16
    __shared__ int sidx[64 * DEG];
    __shared__ float mlp1[UN];
    __shared__ int is_last;

#pragma unroll
    for (int k = 0; k < 2; k++)
        sidx[t * 2 + k] = eidx[((size_t)b * NE + (size_t)node0 * DEG + t * 2 + k) * 2 + 1] & (NN - 1);
    __syncthreads();

    { // gather-aggregate: 16 groups of 32 lanes; group handles 4 nodes
        const int grp = t >> 5, ln = t & 31;
        const u16* xb = xin + (size_t)b * NN * UN;
        for (int it = 0; it < 4; it++) {
            const int nl = grp * 4 + it;
            const int* ip = sidx + nl * DEG;
            uint2 r0 = *(const uint2*)(xb + (size_t)ip[0] * UN + ln * 4);
            float s0 = b2f((u16)(r0.x & 0xffff)), s1 = b2f((u16)(r0.x >> 16));
            float s2 = b2f((u16)(r0.y & 0xffff)), s3 = b2f((u16)(r0.y >> 16));
            float m0 = s0, m1 = s1, m2 = s2, m3 = s3;
#pragma unroll
            for (int e = 1; e < DEG; e++) {
                uint2 r = *(const uint2*)(xb + (size_t)ip[e] * UN + ln * 4);
                float x0 = b2f((u16)(r.x & 0xffff)), x1 = b2f((u16)(r.x >> 16));
                float x2 = b2f((u16)(r.y & 0xffff)), x3 = b2f((u16)(r.y >> 16));
                s0 += x0; s1 += x1; s2 += x2; s3 += x3;
                m0 = fmaxf(m0, x0); m1 = fmaxf(m1, x1);
                m2 = fmaxf(m2, x2); m3 = fmaxf(m3, x3);
            }
            ushort4 os = { f2b(s0), f2b(s1), f2b(s2), f2b(s3) };
            ushort4 om = { f2b(m0), f2b(m1), f2b(m2), f2b(m3) };
            *(ushort4*)(&sS[nl][ln * 4]) = os;
            *(ushort4*)(&sM[nl][ln * 4]) = om;
        }
    }
    __syncthreads();

    // MFMA matmul: wave w -> m-rows (w&3)*16.., nt in [(w>>2)*4, +4)
    const int w = t >> 6, lane = t & 63;
    const int l15 = lane & 15, quad = lane >> 4;
    const int mrow = (w & 3) * 16;
    const int ntbase = (w >> 2) * 4;
    const u16* Bs = AsumT + (size_t)d * UN * UN;
    const u16* Bm = AmaxT + (size_t)d * UN * UN;
    f32x4 acc[4] = {};
#pragma unroll
    for (int k0 = 0; k0 < 4; k0++) {
        short8 aS = *(const short8*)(&sS[mrow + l15][k0 * 32 + quad * 8]);
        short8 aM = *(const short8*)(&sM[mrow + l15][k0 * 32 + quad * 8]);
#pragma unroll
        for (int nt = 0; nt < 4; nt++) {
            const int ng = ntbase + nt;
            short8 bS = *(const short8*)(Bs + (size_t)(ng * 16 + l15) * UN + k0 * 32 + quad * 8);
            short8 bM = *(const short8*)(Bm + (size_t)(ng * 16 + l15) * UN + k0 * 32 + quad * 8);
            acc[nt] = __builtin_amdgcn_mfma_f32_16x16x32_bf16(aS, bS, acc[nt], 0, 0, 0);
            acc[nt] = __builtin_amdgcn_mfma_f32_16x16x32_bf16(aM, bM, acc[nt], 0, 0, 0);
        }
    }

    if (MODE == 1) {
        // epilogue: y = relu(acc+bias)*k + c -> bf16, staged via LDS.
        // C-map: node = mrow + quad*4 + r, unit = ng*16 + l15.
        __syncthreads();
#pragma unroll
        for (int nt = 0; nt < 4; nt++) {
            const int u = (ntbase + nt) * 16 + l15;
            const float bb = biasf[d * UN + u], kk = kv[d * UN + u], cc = cv[d * UN + u];
#pragma unroll
            for (int r = 0; r < 4; r++) {
                float y = fmaxf(acc[nt][r] + bb, 0.0f) * kk + cc;
                sS[mrow + quad * 4 + r][u] = f2b(y);
            }
        }
        __syncthreads();
#pragma unroll
        for (int p = 0; p < 2; p++) {
            int r = (t >> 4) + p * 32;
            int c0 = (t & 15) * 8;
            *(uint4*)(xout + ((size_t)b * NN + node0 + r) * UN + c0) =
                *(const uint4*)(&sS[r][c0]);
        }
    } else {
        // fused readout stage 1: per-unit sum of y over this tile's 64 nodes
        float ps[4];
#pragma unroll
        for (int nt = 0; nt < 4; nt++) {
            const int u = (ntbase + nt) * 16 + l15;
            const float bb = biasf[d * UN + u], kk = kv[d * UN + u], cc = cv[d * UN + u];
            float s = 0.0f;
#pragma unroll
            for (int r = 0; r < 4; r++)
                s += fmaxf(acc[nt][r] + bb, 0.0f) * kk + cc;
            ps[nt] = s;
        }
        __syncthreads();
        float* red = (float*)sM;   // [16 m-groups][128 units]
#pragma unroll
        for (int nt = 0; nt < 4; nt++)
            red[((w & 3) * 4 + quad) * UN + (ntbase + nt) * 16 + l15] = ps[nt];
        __syncthreads();
        if (t < UN) {
            float s = 0.0f;
#pragma unroll
            for (int g = 0; g < 16; g++)
                s += red[g * UN + t];
            partial[((size_t)b * 64 + tile) * UN + t] = s;
        }
        __syncthreads();
        if (t == 0) {
            __threadfence();                       // release partial stores
            int old = atomicAdd(&counters[b], 1);  // device-scope
            is_last = (old == 63);
        }
        __syncthreads();
        if (is_last) {
            __threadfence();                       // acquire other tiles' partials
            if (t < UN) {
                float s = 0.0f;
                for (int c = 0; c < 64; c++)
                    s += partial[((size_t)b * 64 + c) * UN + t];
                red[t] = s * (1.0f / (float)NN);   // gmean
            }
            __syncthreads();
            if (t < UN) {
                float a = bp1[t];
                for (int j = 0; j < UN; j++)
                    a += red[j] * Wp1[j * UN + t];
                mlp1[t] = fmaxf(a, 0.0f);
            }
            __syncthreads();
            if (t < 64) {
                float o = bp2[t];
                for (int j = 0; j < UN; j++)
                    o += mlp1[j] * Wp2[j * 64 + t];
                out[b * 64 + t] = fmaxf(o, 0.0f);
            }
        }
    }
}

extern "C" void kernel_launch(void* const* d_in, const int* in_sizes, int n_in,
                              void* d_out, int out_size, void* d_ws, size_t ws_size,
                              hipStream_t stream) {
    const float* xattr = (const float*)d_in[0];   // [8,4096,128] fp32
    const int*   eidx  = (const int*)d_in[1];     // [8,65536,2] int32
    const float* W     = (const float*)d_in[2];   // [3,1152,128] fp32
    const float* bias  = (const float*)d_in[3];
    const float* gamma = (const float*)d_in[4];
    const float* beta  = (const float*)d_in[5];
    const float* mmean = (const float*)d_in[6];
    const float* mvar  = (const float*)d_in[7];
    const float* Wp1   = (const float*)d_in[8];   // [128,128]
    const float* bp1   = (const float*)d_in[9];
    const float* Wp2   = (const float*)d_in[10];  // [128,64]
    const float* bp2   = (const float*)d_in[11];
    float* out = (float*)d_out;                   // [8,64] fp32

    u16* AsumT = (u16*)d_ws;                        // 3*128*128 bf16
    u16* AmaxT = AsumT + 3 * UN * UN;               // 3*128*128 bf16
    float* biasf = (float*)(AmaxT + 3 * UN * UN);   // 3*128 fp32
    float* kv = biasf + 3 * UN;
    float* cv = kv + 3 * UN;
    int* counters = (int*)(cv + 3 * UN);            // 16 ints
    float* partial = (float*)(counters + 16);       // [8,64,128] fp32
    u16* bufX = (u16*)(partial + NB * 64 * UN);     // [8,4096,128] bf16
    u16* buf0 = bufX + (size_t)NB * NN * UN;
    u16* buf1 = buf0 + (size_t)NB * NN * UN;

    pna10_prep<<<2432, 256, 0, stream>>>(W, bias, gamma, beta, mmean, mvar, xattr,
                                         AsumT, AmaxT, biasf, kv, cv, bufX, counters);
    pna10_layer<1><<<512, 512, 0, stream>>>(bufX, eidx, AsumT, AmaxT, biasf, kv, cv,
                                            buf0, partial, counters,
                                            Wp1, bp1, Wp2, bp2, out, 0);
    pna10_layer<1><<<512, 512, 0, stream>>>(buf0, eidx, AsumT, AmaxT, biasf, kv, cv,
                                            buf1, partial, counters,
                                            Wp1, bp1, Wp2, bp2, out, 1);
    pna10_layer<2><<<512, 512, 0, stream>>>(buf1, eidx, AsumT, AmaxT, biasf, kv, cv,
                                            (u16*)nullptr, partial, counters,
                                            Wp1, bp1, Wp2, bp2, out, 2);
}